// Round 9
// baseline (516.779 us; speedup 1.0000x reference)
//
#include <hip/hip_runtime.h>

#define NODES 100000
#define NEDGE 1600000
#define ET (NEDGE + NODES)
#define INC 128
#define CC 32
#define HH 4
#define NEG 0.2f

typedef __attribute__((ext_vector_type(8))) short short8;   // 8 bf16 (4 VGPRs)
typedef __attribute__((ext_vector_type(4))) float f32x4;    // MFMA C/D
typedef __attribute__((ext_vector_type(8))) unsigned short u16x8;

// round-to-nearest-even f32 -> bf16 bits
static __device__ inline unsigned short f2bf(float f) {
    unsigned u = __float_as_uint(f);
    u += 0x7FFFu + ((u >> 16) & 1u);
    return (unsigned short)(u >> 16);
}
static __device__ inline float bf2f(unsigned short s) {
    return __uint_as_float((unsigned)s << 16);
}
static __device__ inline unsigned pack2bf(float a, float b) {
    return (unsigned)f2bf(a) | ((unsigned)f2bf(b) << 16);
}

// K1: h = x @ W via bf16 MFMA. a_src/a_dst folded into the GEMM as 8 extra
// B-columns (As[k][h] = sum_c W[k][h*32+c]*att_src[h*32+c], ditto Ad):
// one extra 4-MFMA accumulator replaces the old 128-swizzle epilogue.
__global__ __launch_bounds__(256) void k_proj(const float* __restrict__ x,
        const float* __restrict__ W, const float* __restrict__ att_src,
        const float* __restrict__ att_dst, unsigned short* __restrict__ hb,
        float* __restrict__ a_src, float* __restrict__ a_dst) {
    __shared__ unsigned short Wt[128][136];   // [col][k] bf16
    __shared__ unsigned short Axt[8][128];    // cols: 0-3 As heads, 4-7 Ad heads
    const int tid = threadIdx.x;

    for (int i = tid; i < 128 * 128; i += 256) {
        int k = i >> 7, c = i & 127;
        Wt[c][k] = f2bf(W[i]);
    }
    // 512 (k,head) pairs strided over 256 threads  [round-8 bug: `if(tid<512)`
    // only covered k<64 — half of Axt was uninitialized LDS]
    for (int t = tid; t < 512; t += 256) {
        int k = t >> 2, hd = t & 3;
        float ss = 0.f, sd = 0.f;
        const float* wr = W + k * 128 + hd * 32;
        for (int c = 0; c < 32; ++c) {
            ss = fmaf(wr[c], att_src[hd * 32 + c], ss);
            sd = fmaf(wr[c], att_dst[hd * 32 + c], sd);
        }
        Axt[hd][k] = f2bf(ss);
        Axt[4 + hd][k] = f2bf(sd);
    }
    __syncthreads();

    const int w    = tid >> 6;
    const int lane = tid & 63;
    const int quad = lane >> 4;
    const int l15  = lane & 15;

    for (int base = blockIdx.x * 64; base < NODES; base += gridDim.x * 64) {
        const int arow = base + w * 16 + l15;
        short8 af[4];
        if (arow < NODES) {
            const float* xp = x + (size_t)arow * INC + quad * 8;
            #pragma unroll
            for (int kt = 0; kt < 4; ++kt) {
                float4 u = *(const float4*)(xp + kt * 32);
                float4 v = *(const float4*)(xp + kt * 32 + 4);
                short8 a;
                a[0] = (short)f2bf(u.x); a[1] = (short)f2bf(u.y);
                a[2] = (short)f2bf(u.z); a[3] = (short)f2bf(u.w);
                a[4] = (short)f2bf(v.x); a[5] = (short)f2bf(v.y);
                a[6] = (short)f2bf(v.z); a[7] = (short)f2bf(v.w);
                af[kt] = a;
            }
        } else {
            #pragma unroll
            for (int kt = 0; kt < 4; ++kt) af[kt] = (short8){0,0,0,0,0,0,0,0};
        }

        f32x4 accs[8];
        #pragma unroll
        for (int ct = 0; ct < 8; ++ct) {
            const int gcol = ct * 16 + l15;
            f32x4 acc = {0.f, 0.f, 0.f, 0.f};
            #pragma unroll
            for (int kt = 0; kt < 4; ++kt) {
                short8 bf = *(short8*)(&Wt[gcol][kt * 32 + quad * 8]);
                acc = __builtin_amdgcn_mfma_f32_16x16x32_bf16(af[kt], bf, acc, 0, 0, 0);
            }
            accs[ct] = acc;
        }

        // attention-coefficient columns: cols 0-3 -> a_src, 4-7 -> a_dst
        f32x4 acc9 = {0.f, 0.f, 0.f, 0.f};
        #pragma unroll
        for (int kt = 0; kt < 4; ++kt) {
            short8 bf = (short8){0,0,0,0,0,0,0,0};
            if (l15 < 8)
                bf = *(short8*)(&Axt[l15][kt * 32 + quad * 8]);
            acc9 = __builtin_amdgcn_mfma_f32_16x16x32_bf16(af[kt], bf, acc9, 0, 0, 0);
        }

        const int orow = base + w * 16 + quad * 4;   // + reg

        #pragma unroll
        for (int reg = 0; reg < 4; ++reg) {
            int r = orow + reg;
            if (r < NODES) {
                if (l15 < 4)            a_src[r * HH + l15]       = acc9[reg];
                else if (l15 < 8)       a_dst[r * HH + (l15 - 4)] = acc9[reg];
                ushort4 lo, hi;
                lo.x = f2bf(accs[0][reg]); lo.y = f2bf(accs[2][reg]);
                lo.z = f2bf(accs[4][reg]); lo.w = f2bf(accs[6][reg]);
                hi.x = f2bf(accs[1][reg]); hi.y = f2bf(accs[3][reg]);
                hi.z = f2bf(accs[5][reg]); hi.w = f2bf(accs[7][reg]);
                *(ushort4*)(hb + (size_t)r * INC + l15 * 4) = lo;
                *(ushort4*)(hb + (size_t)r * INC + (16 + l15) * 4) = hi;
            }
        }
    }
}

// K2a: in-degree histogram (self-loops included).
__global__ void k_hist(const int* __restrict__ ei, int* __restrict__ deg) {
    int e = blockIdx.x * blockDim.x + threadIdx.x;
    if (e >= ET) return;
    int d = (e < NEDGE) ? ei[NEDGE + e] : e - NEDGE;
    atomicAdd(&deg[d], 1);
}

// K2b: exclusive prefix sum over deg[N] -> off[N], single 1024-thread block.
__global__ __launch_bounds__(1024) void k_scan(const int* __restrict__ deg,
                                               int* __restrict__ off) {
    __shared__ int bsum[1024];
    const int t = threadIdx.x;
    const int chunk = (NODES + 1023) / 1024;
    const int lo = t * chunk;
    const int hi = min(lo + chunk, NODES);
    int s = 0;
    for (int i = lo; i < hi; ++i) s += deg[i];
    bsum[t] = s;
    __syncthreads();
    for (int d = 1; d < 1024; d <<= 1) {
        int v = (t >= d) ? bsum[t - d] : 0;
        __syncthreads();
        if (t >= d) bsum[t] += v;
        __syncthreads();
    }
    int running = (t > 0) ? bsum[t - 1] : 0;
    for (int i = lo; i < hi; ++i) {
        off[i] = running;
        running += deg[i];
    }
}

// K2c: fill CSR. Per edge: gather a_src[s], a_dst[d] (16B each), compute the
// 4 head p=exp(leaky(logit)), claim a slot with one returning atomic, write
// one 16B entry {src, p01(bf16x2), p23(bf16x2), 0}. No denom atomics — the
// consumer sums p itself.
__global__ void k_fill(const int* __restrict__ ei, const float* __restrict__ a_src,
        const float* __restrict__ a_dst, const int* __restrict__ off,
        int* __restrict__ cur, uint4* __restrict__ csr) {
    int e = blockIdx.x * blockDim.x + threadIdx.x;
    if (e >= ET) return;
    int s, d;
    if (e < NEDGE) { s = ei[e]; d = ei[NEDGE + e]; } else { s = d = e - NEDGE; }
    float4 as = *(const float4*)(a_src + (size_t)s * HH);
    float4 ad = *(const float4*)(a_dst + (size_t)d * HH);
    float v0 = as.x + ad.x; v0 = v0 > 0.f ? v0 : NEG * v0;
    float v1 = as.y + ad.y; v1 = v1 > 0.f ? v1 : NEG * v1;
    float v2 = as.z + ad.z; v2 = v2 > 0.f ? v2 : NEG * v2;
    float v3 = as.w + ad.w; v3 = v3 > 0.f ? v3 : NEG * v3;
    int pos = off[d] + atomicAdd(&cur[d], 1);
    uint4 ent;
    ent.x = (unsigned)s;
    ent.y = pack2bf(__expf(v0), __expf(v1));
    ent.z = pack2bf(__expf(v2), __expf(v3));
    ent.w = 0u;
    csr[pos] = ent;
}

// K3: one 16-lane group per destination node; loop over its CSR slice.
// All 16 lanes read the same 16B entry (broadcast), gather hb[src] (16B/lane,
// 256B/edge), accumulate 8 fp32 regs (2 cols x 4 heads) + per-head denom.
// Epilogue: divide by denom, head-mean, bias, relu, coalesced 8B store.
// ZERO atomics.
__global__ __launch_bounds__(256) void k_scatter(const uint4* __restrict__ csr,
        const int* __restrict__ off, const int* __restrict__ deg,
        const unsigned short* __restrict__ hb, const float* __restrict__ bias,
        float* __restrict__ out) {
    const int n = blockIdx.x * 16 + (threadIdx.x >> 4);
    const int l = threadIdx.x & 15;
    const int base = off[n];
    const int cnt = deg[n];

    float acc[8] = {0.f,0.f,0.f,0.f,0.f,0.f,0.f,0.f};
    float den[4] = {0.f,0.f,0.f,0.f};

    for (int i = 0; i < cnt; ++i) {
        uint4 ent = csr[base + i];                       // uniform -> broadcast
        float p0 = bf2f((unsigned short)(ent.y & 0xFFFF));
        float p1 = bf2f((unsigned short)(ent.y >> 16));
        float p2 = bf2f((unsigned short)(ent.z & 0xFFFF));
        float p3 = bf2f((unsigned short)(ent.z >> 16));
        den[0] += p0; den[1] += p1; den[2] += p2; den[3] += p3;
        u16x8 hv = *(const u16x8*)(hb + (size_t)ent.x * INC + l * 8);
        acc[0] = fmaf(p0, bf2f(hv[0]), acc[0]);
        acc[1] = fmaf(p1, bf2f(hv[1]), acc[1]);
        acc[2] = fmaf(p2, bf2f(hv[2]), acc[2]);
        acc[3] = fmaf(p3, bf2f(hv[3]), acc[3]);
        acc[4] = fmaf(p0, bf2f(hv[4]), acc[4]);
        acc[5] = fmaf(p1, bf2f(hv[5]), acc[5]);
        acc[6] = fmaf(p2, bf2f(hv[6]), acc[6]);
        acc[7] = fmaf(p3, bf2f(hv[7]), acc[7]);
    }

    float r0 = 1.f / (den[0] + 1e-16f);
    float r1 = 1.f / (den[1] + 1e-16f);
    float r2 = 1.f / (den[2] + 1e-16f);
    float r3 = 1.f / (den[3] + 1e-16f);
    float o0 = 0.25f * (acc[0]*r0 + acc[1]*r1 + acc[2]*r2 + acc[3]*r3)
             + bias[2*l];
    float o1 = 0.25f * (acc[4]*r0 + acc[5]*r1 + acc[6]*r2 + acc[7]*r3)
             + bias[2*l + 1];
    float2 ov;
    ov.x = o0 > 0.f ? o0 : 0.f;
    ov.y = o1 > 0.f ? o1 : 0.f;
    *(float2*)(out + (size_t)n * CC + 2*l) = ov;        // 128B/node coalesced
}

extern "C" void kernel_launch(void* const* d_in, const int* in_sizes, int n_in,
                              void* d_out, int out_size, void* d_ws, size_t ws_size,
                              hipStream_t stream) {
    const float* x       = (const float*)d_in[0];
    const int*   ei      = (const int*)d_in[1];
    const float* W       = (const float*)d_in[2];
    const float* att_src = (const float*)d_in[3];
    const float* att_dst = (const float*)d_in[4];
    const float* bias    = (const float*)d_in[5];
    float* out = (float*)d_out;

    uint4* csr          = (uint4*)d_ws;                          // ET*16B = 27.2MB
    unsigned short* hb  = (unsigned short*)(csr + (size_t)ET);   // N*128 bf16
    float* a_src        = (float*)(hb + (size_t)NODES * INC);    // N*4 f32
    float* a_dst        = a_src + (size_t)NODES * HH;            // N*4 f32
    int* deg            = (int*)(a_dst + (size_t)NODES * HH);    // N
    int* cur            = deg + NODES;                           // N
    int* off            = cur + NODES;                           // N

    // zero deg + cur in one contiguous memset
    hipMemsetAsync(deg, 0, sizeof(int) * (size_t)NODES * 2, stream);

    k_proj<<<521, 256, 0, stream>>>(x, W, att_src, att_dst, hb, a_src, a_dst);

    k_hist<<<(ET + 255) / 256, 256, 0, stream>>>(ei, deg);
    k_scan<<<1, 1024, 0, stream>>>(deg, off);
    k_fill<<<(ET + 255) / 256, 256, 0, stream>>>(ei, a_src, a_dst, off, cur, csr);

    k_scatter<<<NODES / 16, 256, 0, stream>>>(csr, off, deg, hb, bias, out);
}

// Round 10
// 339.828 us; speedup vs baseline: 1.5207x; 1.5207x over previous
//
#include <hip/hip_runtime.h>

#define NODES 100000
#define NEDGE 1600000
#define ET (NEDGE + NODES)
#define INC 128
#define CC 32
#define HH 4
#define NEG 0.2f
#define NB 98   // scan blocks: ceil(100000/1024)

typedef __attribute__((ext_vector_type(8))) short short8;   // 8 bf16 (4 VGPRs)
typedef __attribute__((ext_vector_type(4))) float f32x4;    // MFMA C/D
typedef __attribute__((ext_vector_type(8))) unsigned short u16x8;

// round-to-nearest-even f32 -> bf16 bits
static __device__ inline unsigned short f2bf(float f) {
    unsigned u = __float_as_uint(f);
    u += 0x7FFFu + ((u >> 16) & 1u);
    return (unsigned short)(u >> 16);
}
static __device__ inline float bf2f(unsigned short s) {
    return __uint_as_float((unsigned)s << 16);
}
static __device__ inline unsigned pack2bf(float a, float b) {
    return (unsigned)f2bf(a) | ((unsigned)f2bf(b) << 16);
}

// K1: h = x @ W via bf16 MFMA. a_src/a_dst folded into the GEMM as 8 extra
// B-columns.
__global__ __launch_bounds__(256) void k_proj(const float* __restrict__ x,
        const float* __restrict__ W, const float* __restrict__ att_src,
        const float* __restrict__ att_dst, unsigned short* __restrict__ hb,
        float* __restrict__ a_src, float* __restrict__ a_dst) {
    __shared__ unsigned short Wt[128][136];   // [col][k] bf16
    __shared__ unsigned short Axt[8][128];    // cols: 0-3 As heads, 4-7 Ad heads
    const int tid = threadIdx.x;

    for (int i = tid; i < 128 * 128; i += 256) {
        int k = i >> 7, c = i & 127;
        Wt[c][k] = f2bf(W[i]);
    }
    for (int t = tid; t < 512; t += 256) {
        int k = t >> 2, hd = t & 3;
        float ss = 0.f, sd = 0.f;
        const float* wr = W + k * 128 + hd * 32;
        for (int c = 0; c < 32; ++c) {
            ss = fmaf(wr[c], att_src[hd * 32 + c], ss);
            sd = fmaf(wr[c], att_dst[hd * 32 + c], sd);
        }
        Axt[hd][k] = f2bf(ss);
        Axt[4 + hd][k] = f2bf(sd);
    }
    __syncthreads();

    const int w    = tid >> 6;
    const int lane = tid & 63;
    const int quad = lane >> 4;
    const int l15  = lane & 15;

    for (int base = blockIdx.x * 64; base < NODES; base += gridDim.x * 64) {
        const int arow = base + w * 16 + l15;
        short8 af[4];
        if (arow < NODES) {
            const float* xp = x + (size_t)arow * INC + quad * 8;
            #pragma unroll
            for (int kt = 0; kt < 4; ++kt) {
                float4 u = *(const float4*)(xp + kt * 32);
                float4 v = *(const float4*)(xp + kt * 32 + 4);
                short8 a;
                a[0] = (short)f2bf(u.x); a[1] = (short)f2bf(u.y);
                a[2] = (short)f2bf(u.z); a[3] = (short)f2bf(u.w);
                a[4] = (short)f2bf(v.x); a[5] = (short)f2bf(v.y);
                a[6] = (short)f2bf(v.z); a[7] = (short)f2bf(v.w);
                af[kt] = a;
            }
        } else {
            #pragma unroll
            for (int kt = 0; kt < 4; ++kt) af[kt] = (short8){0,0,0,0,0,0,0,0};
        }

        f32x4 accs[8];
        #pragma unroll
        for (int ct = 0; ct < 8; ++ct) {
            const int gcol = ct * 16 + l15;
            f32x4 acc = {0.f, 0.f, 0.f, 0.f};
            #pragma unroll
            for (int kt = 0; kt < 4; ++kt) {
                short8 bf = *(short8*)(&Wt[gcol][kt * 32 + quad * 8]);
                acc = __builtin_amdgcn_mfma_f32_16x16x32_bf16(af[kt], bf, acc, 0, 0, 0);
            }
            accs[ct] = acc;
        }

        f32x4 acc9 = {0.f, 0.f, 0.f, 0.f};
        #pragma unroll
        for (int kt = 0; kt < 4; ++kt) {
            short8 bf = (short8){0,0,0,0,0,0,0,0};
            if (l15 < 8)
                bf = *(short8*)(&Axt[l15][kt * 32 + quad * 8]);
            acc9 = __builtin_amdgcn_mfma_f32_16x16x32_bf16(af[kt], bf, acc9, 0, 0, 0);
        }

        const int orow = base + w * 16 + quad * 4;   // + reg

        #pragma unroll
        for (int reg = 0; reg < 4; ++reg) {
            int r = orow + reg;
            if (r < NODES) {
                if (l15 < 4)            a_src[r * HH + l15]       = acc9[reg];
                else if (l15 < 8)       a_dst[r * HH + (l15 - 4)] = acc9[reg];
                ushort4 lo, hi;
                lo.x = f2bf(accs[0][reg]); lo.y = f2bf(accs[2][reg]);
                lo.z = f2bf(accs[4][reg]); lo.w = f2bf(accs[6][reg]);
                hi.x = f2bf(accs[1][reg]); hi.y = f2bf(accs[3][reg]);
                hi.z = f2bf(accs[5][reg]); hi.w = f2bf(accs[7][reg]);
                *(ushort4*)(hb + (size_t)r * INC + l15 * 4) = lo;
                *(ushort4*)(hb + (size_t)r * INC + (16 + l15) * 4) = hi;
            }
        }
    }
}

// K2a: in-degree histogram (self-loops included).
__global__ void k_hist(const int* __restrict__ ei, int* __restrict__ deg) {
    int e = blockIdx.x * blockDim.x + threadIdx.x;
    if (e >= ET) return;
    int d = (e < NEDGE) ? ei[NEDGE + e] : e - NEDGE;
    atomicAdd(&deg[d], 1);
}

// K2b-1: per-1024-chunk partial sums (98 blocks x 256 thr x int4).
__global__ __launch_bounds__(256) void k_scan_part(const int* __restrict__ deg,
                                                   int* __restrict__ partial) {
    __shared__ int red[4];
    const int t = threadIdx.x;
    const int idx0 = blockIdx.x * 1024 + t * 4;
    int s = 0;
    if (idx0 + 3 < NODES) {
        int4 v = *(const int4*)(deg + idx0);
        s = v.x + v.y + v.z + v.w;
    } else {
        for (int k = 0; k < 4; ++k) if (idx0 + k < NODES) s += deg[idx0 + k];
    }
    #pragma unroll
    for (int o = 32; o; o >>= 1) s += __shfl_down(s, o, 64);
    if ((t & 63) == 0) red[t >> 6] = s;
    __syncthreads();
    if (t == 0) partial[blockIdx.x] = red[0] + red[1] + red[2] + red[3];
}

// K2b-2: exclusive scan of the 98 partials (one tiny block).
__global__ __launch_bounds__(128) void k_scan_base(const int* __restrict__ partial,
                                                   int* __restrict__ basep) {
    __shared__ int buf[128];
    const int t = threadIdx.x;
    int v = (t < NB) ? partial[t] : 0;
    buf[t] = v;
    __syncthreads();
    for (int d = 1; d < 128; d <<= 1) {
        int u = (t >= d) ? buf[t - d] : 0;
        __syncthreads();
        buf[t] += u;
        __syncthreads();
    }
    if (t < NB) basep[t] = buf[t] - v;   // exclusive
}

// K2b-3: per-chunk exclusive scan + chunk base -> off[] (int4 stores).
__global__ __launch_bounds__(256) void k_scan_off(const int* __restrict__ deg,
        const int* __restrict__ basep, int* __restrict__ off) {
    __shared__ int tsum[256];
    const int t = threadIdx.x;
    const int idx0 = blockIdx.x * 1024 + t * 4;
    int v[4] = {0, 0, 0, 0};
    if (idx0 + 3 < NODES) {
        int4 q = *(const int4*)(deg + idx0);
        v[0] = q.x; v[1] = q.y; v[2] = q.z; v[3] = q.w;
    } else {
        for (int k = 0; k < 4; ++k) if (idx0 + k < NODES) v[k] = deg[idx0 + k];
    }
    const int s = v[0] + v[1] + v[2] + v[3];
    tsum[t] = s;
    __syncthreads();
    for (int d = 1; d < 256; d <<= 1) {
        int u = (t >= d) ? tsum[t - d] : 0;
        __syncthreads();
        tsum[t] += u;
        __syncthreads();
    }
    int pre = basep[blockIdx.x] + tsum[t] - s;   // exclusive for this thread
    int4 o;
    o.x = pre;
    o.y = o.x + v[0];
    o.z = o.y + v[1];
    o.w = o.z + v[2];
    if (idx0 + 3 < NODES) {
        *(int4*)(off + idx0) = o;
    } else {
        const int oa[4] = {o.x, o.y, o.z, o.w};
        for (int k = 0; k < 4; ++k) if (idx0 + k < NODES) off[idx0 + k] = oa[k];
    }
}

// K2c: fill CSR. Per edge: gather a_src[s], a_dst[d], compute 4 head
// p=exp(leaky(logit)), claim slot via returning atomic, write one 16B entry.
__global__ void k_fill(const int* __restrict__ ei, const float* __restrict__ a_src,
        const float* __restrict__ a_dst, const int* __restrict__ off,
        int* __restrict__ cur, uint4* __restrict__ csr) {
    int e = blockIdx.x * blockDim.x + threadIdx.x;
    if (e >= ET) return;
    int s, d;
    if (e < NEDGE) { s = ei[e]; d = ei[NEDGE + e]; } else { s = d = e - NEDGE; }
    float4 as = *(const float4*)(a_src + (size_t)s * HH);
    float4 ad = *(const float4*)(a_dst + (size_t)d * HH);
    float v0 = as.x + ad.x; v0 = v0 > 0.f ? v0 : NEG * v0;
    float v1 = as.y + ad.y; v1 = v1 > 0.f ? v1 : NEG * v1;
    float v2 = as.z + ad.z; v2 = v2 > 0.f ? v2 : NEG * v2;
    float v3 = as.w + ad.w; v3 = v3 > 0.f ? v3 : NEG * v3;
    int pos = off[d] + atomicAdd(&cur[d], 1);
    uint4 ent;
    ent.x = (unsigned)s;
    ent.y = pack2bf(__expf(v0), __expf(v1));
    ent.z = pack2bf(__expf(v2), __expf(v3));
    ent.w = 0u;
    csr[pos] = ent;
}

// K3: one 16-lane group per destination node; 2x-unrolled CSR loop (two
// independent ent+gather chains in flight). fp32 register accumulation,
// fused denom + head-mean + bias + relu + coalesced store. ZERO atomics.
__global__ __launch_bounds__(256) void k_scatter(const uint4* __restrict__ csr,
        const int* __restrict__ off, const int* __restrict__ deg,
        const unsigned short* __restrict__ hb, const float* __restrict__ bias,
        float* __restrict__ out) {
    const int n = blockIdx.x * 16 + (threadIdx.x >> 4);
    const int l = threadIdx.x & 15;
    const int cbase = off[n];
    const int cnt = deg[n];

    float acc[8] = {0.f,0.f,0.f,0.f,0.f,0.f,0.f,0.f};
    float den[4] = {0.f,0.f,0.f,0.f};

    int i = 0;
    for (; i + 2 <= cnt; i += 2) {
        uint4 e0 = csr[cbase + i];
        uint4 e1 = csr[cbase + i + 1];
        u16x8 h0 = *(const u16x8*)(hb + (size_t)e0.x * INC + l * 8);
        u16x8 h1 = *(const u16x8*)(hb + (size_t)e1.x * INC + l * 8);
        float p0 = bf2f((unsigned short)(e0.y & 0xFFFF));
        float p1 = bf2f((unsigned short)(e0.y >> 16));
        float p2 = bf2f((unsigned short)(e0.z & 0xFFFF));
        float p3 = bf2f((unsigned short)(e0.z >> 16));
        den[0] += p0; den[1] += p1; den[2] += p2; den[3] += p3;
        acc[0] = fmaf(p0, bf2f(h0[0]), acc[0]);
        acc[1] = fmaf(p1, bf2f(h0[1]), acc[1]);
        acc[2] = fmaf(p2, bf2f(h0[2]), acc[2]);
        acc[3] = fmaf(p3, bf2f(h0[3]), acc[3]);
        acc[4] = fmaf(p0, bf2f(h0[4]), acc[4]);
        acc[5] = fmaf(p1, bf2f(h0[5]), acc[5]);
        acc[6] = fmaf(p2, bf2f(h0[6]), acc[6]);
        acc[7] = fmaf(p3, bf2f(h0[7]), acc[7]);
        float q0 = bf2f((unsigned short)(e1.y & 0xFFFF));
        float q1 = bf2f((unsigned short)(e1.y >> 16));
        float q2 = bf2f((unsigned short)(e1.z & 0xFFFF));
        float q3 = bf2f((unsigned short)(e1.z >> 16));
        den[0] += q0; den[1] += q1; den[2] += q2; den[3] += q3;
        acc[0] = fmaf(q0, bf2f(h1[0]), acc[0]);
        acc[1] = fmaf(q1, bf2f(h1[1]), acc[1]);
        acc[2] = fmaf(q2, bf2f(h1[2]), acc[2]);
        acc[3] = fmaf(q3, bf2f(h1[3]), acc[3]);
        acc[4] = fmaf(q0, bf2f(h1[4]), acc[4]);
        acc[5] = fmaf(q1, bf2f(h1[5]), acc[5]);
        acc[6] = fmaf(q2, bf2f(h1[6]), acc[6]);
        acc[7] = fmaf(q3, bf2f(h1[7]), acc[7]);
    }
    if (i < cnt) {
        uint4 e0 = csr[cbase + i];
        u16x8 h0 = *(const u16x8*)(hb + (size_t)e0.x * INC + l * 8);
        float p0 = bf2f((unsigned short)(e0.y & 0xFFFF));
        float p1 = bf2f((unsigned short)(e0.y >> 16));
        float p2 = bf2f((unsigned short)(e0.z & 0xFFFF));
        float p3 = bf2f((unsigned short)(e0.z >> 16));
        den[0] += p0; den[1] += p1; den[2] += p2; den[3] += p3;
        acc[0] = fmaf(p0, bf2f(h0[0]), acc[0]);
        acc[1] = fmaf(p1, bf2f(h0[1]), acc[1]);
        acc[2] = fmaf(p2, bf2f(h0[2]), acc[2]);
        acc[3] = fmaf(p3, bf2f(h0[3]), acc[3]);
        acc[4] = fmaf(p0, bf2f(h0[4]), acc[4]);
        acc[5] = fmaf(p1, bf2f(h0[5]), acc[5]);
        acc[6] = fmaf(p2, bf2f(h0[6]), acc[6]);
        acc[7] = fmaf(p3, bf2f(h0[7]), acc[7]);
    }

    float r0 = 1.f / (den[0] + 1e-16f);
    float r1 = 1.f / (den[1] + 1e-16f);
    float r2 = 1.f / (den[2] + 1e-16f);
    float r3 = 1.f / (den[3] + 1e-16f);
    float o0 = 0.25f * (acc[0]*r0 + acc[1]*r1 + acc[2]*r2 + acc[3]*r3)
             + bias[2*l];
    float o1 = 0.25f * (acc[4]*r0 + acc[5]*r1 + acc[6]*r2 + acc[7]*r3)
             + bias[2*l + 1];
    float2 ov;
    ov.x = o0 > 0.f ? o0 : 0.f;
    ov.y = o1 > 0.f ? o1 : 0.f;
    *(float2*)(out + (size_t)n * CC + 2*l) = ov;        // 128B/node coalesced
}

extern "C" void kernel_launch(void* const* d_in, const int* in_sizes, int n_in,
                              void* d_out, int out_size, void* d_ws, size_t ws_size,
                              hipStream_t stream) {
    const float* x       = (const float*)d_in[0];
    const int*   ei      = (const int*)d_in[1];
    const float* W       = (const float*)d_in[2];
    const float* att_src = (const float*)d_in[3];
    const float* att_dst = (const float*)d_in[4];
    const float* bias    = (const float*)d_in[5];
    float* out = (float*)d_out;

    uint4* csr          = (uint4*)d_ws;                          // ET*16B = 27.2MB
    unsigned short* hb  = (unsigned short*)(csr + (size_t)ET);   // N*128 bf16
    float* a_src        = (float*)(hb + (size_t)NODES * INC);    // N*4 f32
    float* a_dst        = a_src + (size_t)NODES * HH;            // N*4 f32
    int* deg            = (int*)(a_dst + (size_t)NODES * HH);    // N
    int* cur            = deg + NODES;                           // N
    int* off            = cur + NODES;                           // N
    int* partial        = off + NODES;                           // NB
    int* basep          = partial + NB;                          // NB

    hipMemsetAsync(deg, 0, sizeof(int) * (size_t)NODES * 2, stream);

    k_proj<<<521, 256, 0, stream>>>(x, W, att_src, att_dst, hb, a_src, a_dst);

    k_hist<<<(ET + 255) / 256, 256, 0, stream>>>(ei, deg);
    k_scan_part<<<NB, 256, 0, stream>>>(deg, partial);
    k_scan_base<<<1, 128, 0, stream>>>(partial, basep);
    k_scan_off<<<NB, 256, 0, stream>>>(deg, basep, off);
    k_fill<<<(ET + 255) / 256, 256, 0, stream>>>(ei, a_src, a_dst, off, cur, csr);

    k_scatter<<<NODES / 16, 256, 0, stream>>>(csr, off, deg, hb, bias, out);
}

// Round 11
// 311.910 us; speedup vs baseline: 1.6568x; 1.0895x over previous
//
#include <hip/hip_runtime.h>

#define NODES 100000
#define NEDGE 1600000
#define ET (NEDGE + NODES)
#define INC 128
#define CC 32
#define HH 4
#define NEG 0.2f
#define NB 98   // scan blocks: ceil(100000/1024)

typedef __attribute__((ext_vector_type(8))) short short8;   // 8 bf16 (4 VGPRs)
typedef __attribute__((ext_vector_type(4))) float f32x4;    // MFMA C/D
typedef __attribute__((ext_vector_type(8))) unsigned short u16x8;

// round-to-nearest-even f32 -> bf16 bits
static __device__ inline unsigned short f2bf(float f) {
    unsigned u = __float_as_uint(f);
    u += 0x7FFFu + ((u >> 16) & 1u);
    return (unsigned short)(u >> 16);
}
static __device__ inline float bf2f(unsigned short s) {
    return __uint_as_float((unsigned)s << 16);
}
static __device__ inline float lexp(float v) {
    v = v > 0.f ? v : NEG * v;
    return __expf(v);
}

// K1: h = x @ W via bf16 MFMA. a_src/a_dst folded into the GEMM as 8 extra
// B-columns; epilogue writes them to the compact av[n][8] table (fp32).
__global__ __launch_bounds__(256) void k_proj(const float* __restrict__ x,
        const float* __restrict__ W, const float* __restrict__ att_src,
        const float* __restrict__ att_dst, unsigned short* __restrict__ hb,
        float* __restrict__ av) {
    __shared__ unsigned short Wt[128][136];   // [col][k] bf16
    __shared__ unsigned short Axt[8][128];    // cols: 0-3 As heads, 4-7 Ad heads
    const int tid = threadIdx.x;

    for (int i = tid; i < 128 * 128; i += 256) {
        int k = i >> 7, c = i & 127;
        Wt[c][k] = f2bf(W[i]);
    }
    for (int t = tid; t < 512; t += 256) {
        int k = t >> 2, hd = t & 3;
        float ss = 0.f, sd = 0.f;
        const float* wr = W + k * 128 + hd * 32;
        for (int c = 0; c < 32; ++c) {
            ss = fmaf(wr[c], att_src[hd * 32 + c], ss);
            sd = fmaf(wr[c], att_dst[hd * 32 + c], sd);
        }
        Axt[hd][k] = f2bf(ss);
        Axt[4 + hd][k] = f2bf(sd);
    }
    __syncthreads();

    const int w    = tid >> 6;
    const int lane = tid & 63;
    const int quad = lane >> 4;
    const int l15  = lane & 15;

    for (int base = blockIdx.x * 64; base < NODES; base += gridDim.x * 64) {
        const int arow = base + w * 16 + l15;
        short8 af[4];
        if (arow < NODES) {
            const float* xp = x + (size_t)arow * INC + quad * 8;
            #pragma unroll
            for (int kt = 0; kt < 4; ++kt) {
                float4 u = *(const float4*)(xp + kt * 32);
                float4 v = *(const float4*)(xp + kt * 32 + 4);
                short8 a;
                a[0] = (short)f2bf(u.x); a[1] = (short)f2bf(u.y);
                a[2] = (short)f2bf(u.z); a[3] = (short)f2bf(u.w);
                a[4] = (short)f2bf(v.x); a[5] = (short)f2bf(v.y);
                a[6] = (short)f2bf(v.z); a[7] = (short)f2bf(v.w);
                af[kt] = a;
            }
        } else {
            #pragma unroll
            for (int kt = 0; kt < 4; ++kt) af[kt] = (short8){0,0,0,0,0,0,0,0};
        }

        f32x4 accs[8];
        #pragma unroll
        for (int ct = 0; ct < 8; ++ct) {
            const int gcol = ct * 16 + l15;
            f32x4 acc = {0.f, 0.f, 0.f, 0.f};
            #pragma unroll
            for (int kt = 0; kt < 4; ++kt) {
                short8 bf = *(short8*)(&Wt[gcol][kt * 32 + quad * 8]);
                acc = __builtin_amdgcn_mfma_f32_16x16x32_bf16(af[kt], bf, acc, 0, 0, 0);
            }
            accs[ct] = acc;
        }

        f32x4 acc9 = {0.f, 0.f, 0.f, 0.f};
        #pragma unroll
        for (int kt = 0; kt < 4; ++kt) {
            short8 bf = (short8){0,0,0,0,0,0,0,0};
            if (l15 < 8)
                bf = *(short8*)(&Axt[l15][kt * 32 + quad * 8]);
            acc9 = __builtin_amdgcn_mfma_f32_16x16x32_bf16(af[kt], bf, acc9, 0, 0, 0);
        }

        const int orow = base + w * 16 + quad * 4;   // + reg

        #pragma unroll
        for (int reg = 0; reg < 4; ++reg) {
            int r = orow + reg;
            if (r < NODES) {
                if (l15 < 8) av[(size_t)r * 8 + l15] = acc9[reg];  // as[0-3], ad[4-7]
                ushort4 lo, hi;
                lo.x = f2bf(accs[0][reg]); lo.y = f2bf(accs[2][reg]);
                lo.z = f2bf(accs[4][reg]); lo.w = f2bf(accs[6][reg]);
                hi.x = f2bf(accs[1][reg]); hi.y = f2bf(accs[3][reg]);
                hi.z = f2bf(accs[5][reg]); hi.w = f2bf(accs[7][reg]);
                *(ushort4*)(hb + (size_t)r * INC + l15 * 4) = lo;
                *(ushort4*)(hb + (size_t)r * INC + (16 + l15) * 4) = hi;
            }
        }
    }
}

// K2a: rank pass — ONE returning atomic per edge builds both the in-degree
// histogram and each edge's within-node rank (coalesced 4B store).
__global__ void k_rank(const int* __restrict__ ei, int* __restrict__ deg,
                       int* __restrict__ rank) {
    int e = blockIdx.x * blockDim.x + threadIdx.x;
    if (e >= ET) return;
    int d = (e < NEDGE) ? ei[NEDGE + e] : e - NEDGE;
    rank[e] = atomicAdd(&deg[d], 1);
}

// K2b-1: per-1024-chunk partial sums.
__global__ __launch_bounds__(256) void k_scan_part(const int* __restrict__ deg,
                                                   int* __restrict__ partial) {
    __shared__ int red[4];
    const int t = threadIdx.x;
    const int idx0 = blockIdx.x * 1024 + t * 4;
    int s = 0;
    if (idx0 + 3 < NODES) {
        int4 v = *(const int4*)(deg + idx0);
        s = v.x + v.y + v.z + v.w;
    } else {
        for (int k = 0; k < 4; ++k) if (idx0 + k < NODES) s += deg[idx0 + k];
    }
    #pragma unroll
    for (int o = 32; o; o >>= 1) s += __shfl_down(s, o, 64);
    if ((t & 63) == 0) red[t >> 6] = s;
    __syncthreads();
    if (t == 0) partial[blockIdx.x] = red[0] + red[1] + red[2] + red[3];
}

// K2b-2: exclusive scan of the 98 partials.
__global__ __launch_bounds__(128) void k_scan_base(const int* __restrict__ partial,
                                                   int* __restrict__ basep) {
    __shared__ int buf[128];
    const int t = threadIdx.x;
    int v = (t < NB) ? partial[t] : 0;
    buf[t] = v;
    __syncthreads();
    for (int d = 1; d < 128; d <<= 1) {
        int u = (t >= d) ? buf[t - d] : 0;
        __syncthreads();
        buf[t] += u;
        __syncthreads();
    }
    if (t < NB) basep[t] = buf[t] - v;   // exclusive
}

// K2b-3: per-chunk exclusive scan + chunk base -> off[].
__global__ __launch_bounds__(256) void k_scan_off(const int* __restrict__ deg,
        const int* __restrict__ basep, int* __restrict__ off) {
    __shared__ int tsum[256];
    const int t = threadIdx.x;
    const int idx0 = blockIdx.x * 1024 + t * 4;
    int v[4] = {0, 0, 0, 0};
    if (idx0 + 3 < NODES) {
        int4 q = *(const int4*)(deg + idx0);
        v[0] = q.x; v[1] = q.y; v[2] = q.z; v[3] = q.w;
    } else {
        for (int k = 0; k < 4; ++k) if (idx0 + k < NODES) v[k] = deg[idx0 + k];
    }
    const int s = v[0] + v[1] + v[2] + v[3];
    tsum[t] = s;
    __syncthreads();
    for (int d = 1; d < 256; d <<= 1) {
        int u = (t >= d) ? tsum[t - d] : 0;
        __syncthreads();
        tsum[t] += u;
        __syncthreads();
    }
    int pre = basep[blockIdx.x] + tsum[t] - s;
    int4 o;
    o.x = pre;
    o.y = o.x + v[0];
    o.z = o.y + v[1];
    o.w = o.z + v[2];
    if (idx0 + 3 < NODES) {
        *(int4*)(off + idx0) = o;
    } else {
        const int oa[4] = {o.x, o.y, o.z, o.w};
        for (int k = 0; k < 4; ++k) if (idx0 + k < NODES) off[idx0 + k] = oa[k];
    }
}

// K2c: place pass — zero atomics; slot = off[d] + rank[e]; entry is 4B (src).
// csr4 is 6.8 MB total (node slice ~68B) so lines stay L2-resident between
// the ~16 writes each receives.
__global__ void k_place(const int* __restrict__ ei, const int* __restrict__ rank,
        const int* __restrict__ off, int* __restrict__ csr4) {
    int e = blockIdx.x * blockDim.x + threadIdx.x;
    if (e >= ET) return;
    int s, d;
    if (e < NEDGE) { s = ei[e]; d = ei[NEDGE + e]; } else { s = d = e - NEDGE; }
    csr4[off[d] + rank[e]] = s;
}

// K3: one 16-lane group per dst node. Per edge: 4B src broadcast, 16B av[src]
// broadcast (L2-resident), p = exp(leaky(as+ad)) in fp32 per lane (redundant
// VALU, hidden under gather latency), 16B/lane hb gather, fp32 accumulate.
// Fused denom + head-mean + bias + relu + coalesced store. ZERO atomics.
__global__ __launch_bounds__(256) void k_scatter(const int* __restrict__ csr4,
        const int* __restrict__ off, const int* __restrict__ deg,
        const unsigned short* __restrict__ hb, const float* __restrict__ av,
        const float* __restrict__ bias, float* __restrict__ out) {
    const int n = blockIdx.x * 16 + (threadIdx.x >> 4);
    const int l = threadIdx.x & 15;
    const int cbase = off[n];
    const int cnt = deg[n];
    const float4 ad = *(const float4*)(av + (size_t)n * 8 + 4);

    float acc[8] = {0.f,0.f,0.f,0.f,0.f,0.f,0.f,0.f};
    float den[4] = {0.f,0.f,0.f,0.f};

    int i = 0;
    for (; i + 2 <= cnt; i += 2) {
        int s0 = csr4[cbase + i];
        int s1 = csr4[cbase + i + 1];
        float4 as0 = *(const float4*)(av + (size_t)s0 * 8);
        float4 as1 = *(const float4*)(av + (size_t)s1 * 8);
        u16x8 h0 = *(const u16x8*)(hb + (size_t)s0 * INC + l * 8);
        u16x8 h1 = *(const u16x8*)(hb + (size_t)s1 * INC + l * 8);
        float p0 = lexp(as0.x + ad.x), p1 = lexp(as0.y + ad.y);
        float p2 = lexp(as0.z + ad.z), p3 = lexp(as0.w + ad.w);
        den[0] += p0; den[1] += p1; den[2] += p2; den[3] += p3;
        acc[0] = fmaf(p0, bf2f(h0[0]), acc[0]);
        acc[1] = fmaf(p1, bf2f(h0[1]), acc[1]);
        acc[2] = fmaf(p2, bf2f(h0[2]), acc[2]);
        acc[3] = fmaf(p3, bf2f(h0[3]), acc[3]);
        acc[4] = fmaf(p0, bf2f(h0[4]), acc[4]);
        acc[5] = fmaf(p1, bf2f(h0[5]), acc[5]);
        acc[6] = fmaf(p2, bf2f(h0[6]), acc[6]);
        acc[7] = fmaf(p3, bf2f(h0[7]), acc[7]);
        float q0 = lexp(as1.x + ad.x), q1 = lexp(as1.y + ad.y);
        float q2 = lexp(as1.z + ad.z), q3 = lexp(as1.w + ad.w);
        den[0] += q0; den[1] += q1; den[2] += q2; den[3] += q3;
        acc[0] = fmaf(q0, bf2f(h1[0]), acc[0]);
        acc[1] = fmaf(q1, bf2f(h1[1]), acc[1]);
        acc[2] = fmaf(q2, bf2f(h1[2]), acc[2]);
        acc[3] = fmaf(q3, bf2f(h1[3]), acc[3]);
        acc[4] = fmaf(q0, bf2f(h1[4]), acc[4]);
        acc[5] = fmaf(q1, bf2f(h1[5]), acc[5]);
        acc[6] = fmaf(q2, bf2f(h1[6]), acc[6]);
        acc[7] = fmaf(q3, bf2f(h1[7]), acc[7]);
    }
    if (i < cnt) {
        int s0 = csr4[cbase + i];
        float4 as0 = *(const float4*)(av + (size_t)s0 * 8);
        u16x8 h0 = *(const u16x8*)(hb + (size_t)s0 * INC + l * 8);
        float p0 = lexp(as0.x + ad.x), p1 = lexp(as0.y + ad.y);
        float p2 = lexp(as0.z + ad.z), p3 = lexp(as0.w + ad.w);
        den[0] += p0; den[1] += p1; den[2] += p2; den[3] += p3;
        acc[0] = fmaf(p0, bf2f(h0[0]), acc[0]);
        acc[1] = fmaf(p1, bf2f(h0[1]), acc[1]);
        acc[2] = fmaf(p2, bf2f(h0[2]), acc[2]);
        acc[3] = fmaf(p3, bf2f(h0[3]), acc[3]);
        acc[4] = fmaf(p0, bf2f(h0[4]), acc[4]);
        acc[5] = fmaf(p1, bf2f(h0[5]), acc[5]);
        acc[6] = fmaf(p2, bf2f(h0[6]), acc[6]);
        acc[7] = fmaf(p3, bf2f(h0[7]), acc[7]);
    }

    float r0 = 1.f / (den[0] + 1e-16f);
    float r1 = 1.f / (den[1] + 1e-16f);
    float r2 = 1.f / (den[2] + 1e-16f);
    float r3 = 1.f / (den[3] + 1e-16f);
    float o0 = 0.25f * (acc[0]*r0 + acc[1]*r1 + acc[2]*r2 + acc[3]*r3)
             + bias[2*l];
    float o1 = 0.25f * (acc[4]*r0 + acc[5]*r1 + acc[6]*r2 + acc[7]*r3)
             + bias[2*l + 1];
    float2 ov;
    ov.x = o0 > 0.f ? o0 : 0.f;
    ov.y = o1 > 0.f ? o1 : 0.f;
    *(float2*)(out + (size_t)n * CC + 2*l) = ov;
}

extern "C" void kernel_launch(void* const* d_in, const int* in_sizes, int n_in,
                              void* d_out, int out_size, void* d_ws, size_t ws_size,
                              hipStream_t stream) {
    const float* x       = (const float*)d_in[0];
    const int*   ei      = (const int*)d_in[1];
    const float* W       = (const float*)d_in[2];
    const float* att_src = (const float*)d_in[3];
    const float* att_dst = (const float*)d_in[4];
    const float* bias    = (const float*)d_in[5];
    float* out = (float*)d_out;

    int* csr4           = (int*)d_ws;                            // ET = 6.8 MB
    unsigned short* hb  = (unsigned short*)(csr4 + (size_t)ET);  // N*128 bf16
    float* av           = (float*)(hb + (size_t)NODES * INC);    // N*8 f32
    int* deg            = (int*)(av + (size_t)NODES * 8);        // N
    int* off            = deg + NODES;                           // N
    int* rank           = off + NODES;                           // ET
    int* partial        = rank + ET;                             // NB
    int* basep          = partial + NB;                          // NB

    hipMemsetAsync(deg, 0, sizeof(int) * (size_t)NODES, stream);

    k_proj<<<521, 256, 0, stream>>>(x, W, att_src, att_dst, hb, av);

    k_rank<<<(ET + 255) / 256, 256, 0, stream>>>(ei, deg, rank);
    k_scan_part<<<NB, 256, 0, stream>>>(deg, partial);
    k_scan_base<<<1, 128, 0, stream>>>(partial, basep);
    k_scan_off<<<NB, 256, 0, stream>>>(deg, basep, off);
    k_place<<<(ET + 255) / 256, 256, 0, stream>>>(ei, rank, off, csr4);

    k_scatter<<<NODES / 16, 256, 0, stream>>>(csr4, off, deg, hb, av, bias, out);
}